// Round 1
// baseline (1888.263 us; speedup 1.0000x reference)
//
#include <hip/hip_runtime.h>

// MultiTaskVQAModel: v/q projections -> Mutan fusion (rank 15) -> per-question-type heads.
// bf16 MFMA pipeline, fp32 accumulate. B=4096.

using u16 = unsigned short;
typedef __bf16 b16x8 __attribute__((ext_vector_type(8)));
typedef float f32x4 __attribute__((ext_vector_type(4)));

static __device__ __forceinline__ u16 f2bf(float f) {
  unsigned int u = __builtin_bit_cast(unsigned int, f);
  u = (u + 0x7fffu + ((u >> 16) & 1u)) >> 16;   // round-to-nearest-even
  return (u16)u;
}

static __device__ __forceinline__ void gload_lds16(const u16* g, u16* l) {
  __builtin_amdgcn_global_load_lds((__attribute__((address_space(1))) void*)(g),
                                   (__attribute__((address_space(3))) void*)(l), 16, 0, 0);
}

// ---------------- conversion / padding kernels ----------------

// dst [Nd,Kd] bf16 = pad(src [Ns,Ks] f32); Kd % 8 == 0
__global__ void cvt_pad_kernel(const float* __restrict__ src, u16* __restrict__ dst,
                               int Ns, int Ks, int Nd, int Kd) {
  long long idx = (long long)blockIdx.x * blockDim.x + threadIdx.x;
  long long total = ((long long)Nd * Kd) >> 3;
  if (idx >= total) return;
  long long e = idx << 3;
  int r = (int)(e / Kd);
  int c = (int)(e - (long long)r * Kd);
  u16 v[8];
  if (r < Ns && c + 8 <= Ks) {
    const float* s = src + (long long)r * Ks + c;
#pragma unroll
    for (int i = 0; i < 8; ++i) v[i] = f2bf(s[i]);
  } else {
#pragma unroll
    for (int i = 0; i < 8; ++i) {
      int cc = c + i;
      float f = (r < Ns && cc < Ks) ? src[(long long)r * Ks + cc] : 0.f;
      v[i] = f2bf(f);
    }
  }
  uint4 o;
  o.x = (unsigned)v[0] | ((unsigned)v[1] << 16);
  o.y = (unsigned)v[2] | ((unsigned)v[3] << 16);
  o.z = (unsigned)v[4] | ((unsigned)v[5] << 16);
  o.w = (unsigned)v[6] | ((unsigned)v[7] << 16);
  *reinterpret_cast<uint4*>(dst + e) = o;
}

__global__ void pad_f32_kernel(const float* __restrict__ src, float* __restrict__ dst,
                               int Ns, int Nd) {
  int i = blockIdx.x * blockDim.x + threadIdx.x;
  if (i < Nd) dst[i] = (i < Ns) ? src[i] : 0.f;
}

// ---------------- generic bf16 GEMM: C = act(A @ B^T + bias) ----------------
// A [M,K] bf16 (K%32==0), B [Npad,K] bf16 (Npad%128==0, zero-padded), bias f32 [Npad-safe]
// 128x128 tile, 4 waves of 64x64, mfma 16x16x32.
template <int TANH, int OUT_BF16>
__global__ __launch_bounds__(256) void gemm_bt_kernel(
    const u16* __restrict__ A, const u16* __restrict__ B,
    const float* __restrict__ bias, void* __restrict__ Cv,
    int K, int Nout, int Nfill, int ldc) {
  __shared__ u16 sA[128 * 32];
  __shared__ u16 sB[128 * 32];
  const int tid = threadIdx.x;
  const int wid = tid >> 6;
  const int lane = tid & 63;
  const long long brow = (long long)blockIdx.y * 128;
  const long long bcol = (long long)blockIdx.x * 128;
  const int wr = (wid >> 1) * 64;
  const int wc = (wid & 1) * 64;
  const int lr = lane & 15;
  const int ko = (lane >> 4) * 8;

  f32x4 acc[4][4];
#pragma unroll
  for (int i = 0; i < 4; ++i)
#pragma unroll
    for (int j = 0; j < 4; ++j)
#pragma unroll
      for (int q = 0; q < 4; ++q) acc[i][j][q] = 0.f;

  for (int k0 = 0; k0 < K; k0 += 32) {
    __syncthreads();
#pragma unroll
    for (int j = 0; j < 2; ++j) {
      const int c = j * 256 + tid;
      const int r = c >> 2;
      const int kc = (c & 3) * 8;
      gload_lds16(A + (brow + r) * K + k0 + kc, sA + c * 8);
      gload_lds16(B + (bcol + r) * K + k0 + kc, sB + c * 8);
    }
    __syncthreads();
    b16x8 af[4], bfr[4];
#pragma unroll
    for (int i = 0; i < 4; ++i) {
      af[i]  = *reinterpret_cast<const b16x8*>(&sA[(wr + i * 16 + lr) * 32 + ko]);
      bfr[i] = *reinterpret_cast<const b16x8*>(&sB[(wc + i * 16 + lr) * 32 + ko]);
    }
#pragma unroll
    for (int i = 0; i < 4; ++i)
#pragma unroll
      for (int j = 0; j < 4; ++j)
        acc[i][j] = __builtin_amdgcn_mfma_f32_16x16x32_bf16(af[i], bfr[j], acc[i][j], 0, 0, 0);
  }

  const int rbase = wr + (lane >> 4) * 4;
#pragma unroll
  for (int i = 0; i < 4; ++i) {
#pragma unroll
    for (int j = 0; j < 4; ++j) {
      const long long col = bcol + wc + j * 16 + lr;
      if (col < Nfill) {
        const float bb = (col < Nout) ? bias[col] : 0.f;
#pragma unroll
        for (int q = 0; q < 4; ++q) {
          float v = acc[i][j][q] + bb;
          if (TANH) v = tanhf(v);
          if (col >= Nout) v = 0.f;
          const long long row = brow + rbase + i * 16 + q;
          if (OUT_BF16)
            reinterpret_cast<u16*>(Cv)[row * ldc + col] = f2bf(v);
          else
            reinterpret_cast<float*>(Cv)[row * ldc + col] = v;
        }
      }
    }
  }
}

// ---------------- fused Mutan z kernel ----------------
// z[b,d] = sum_r (h0@Wm0^T + bm0)[b, r*1600+d] * (h1@Wm1^T + bm1)[b, r*1600+d]
// tile: 128 (b) x 64 (d); 4 waves of 64x32; K = 1600.
__global__ __launch_bounds__(256) void mutan_z_kernel(
    const u16* __restrict__ H0, const u16* __restrict__ H1,
    const u16* __restrict__ Wm0, const u16* __restrict__ Wm1,
    const float* __restrict__ bm0, const float* __restrict__ bm1,
    u16* __restrict__ Z) {
  __shared__ u16 sA0[128 * 32], sA1[128 * 32], sB0[64 * 32], sB1[64 * 32];
  const int tid = threadIdx.x;
  const int wid = tid >> 6;
  const int lane = tid & 63;
  const long long brow = (long long)blockIdx.y * 128;
  const int bcol = blockIdx.x * 64;
  const int wr = (wid >> 1) * 64;
  const int wc = (wid & 1) * 32;
  const int lr = lane & 15;
  const int ko = (lane >> 4) * 8;
  const int K = 1600;

  f32x4 zac[4][2];
#pragma unroll
  for (int i = 0; i < 4; ++i)
#pragma unroll
    for (int j = 0; j < 2; ++j)
#pragma unroll
      for (int q = 0; q < 4; ++q) zac[i][j][q] = 0.f;

  for (int r = 0; r < 15; ++r) {
    f32x4 p0[4][2], p1[4][2];
#pragma unroll
    for (int i = 0; i < 4; ++i)
#pragma unroll
      for (int j = 0; j < 2; ++j)
#pragma unroll
        for (int q = 0; q < 4; ++q) { p0[i][j][q] = 0.f; p1[i][j][q] = 0.f; }

    const long long wrow = (long long)r * 1600 + bcol;
    for (int k0 = 0; k0 < K; k0 += 32) {
      __syncthreads();
#pragma unroll
      for (int j = 0; j < 2; ++j) {
        const int c = j * 256 + tid;
        const int rr = c >> 2;
        const int kc = (c & 3) * 8;
        gload_lds16(H0 + (brow + rr) * K + k0 + kc, sA0 + c * 8);
        gload_lds16(H1 + (brow + rr) * K + k0 + kc, sA1 + c * 8);
      }
      {
        const int c = tid;
        const int rr = c >> 2;
        const int kc = (c & 3) * 8;
        gload_lds16(Wm0 + (wrow + rr) * K + k0 + kc, sB0 + c * 8);
        gload_lds16(Wm1 + (wrow + rr) * K + k0 + kc, sB1 + c * 8);
      }
      __syncthreads();
      b16x8 a0[4], a1[4], b0[2], b1[2];
#pragma unroll
      for (int i = 0; i < 4; ++i) {
        a0[i] = *reinterpret_cast<const b16x8*>(&sA0[(wr + i * 16 + lr) * 32 + ko]);
        a1[i] = *reinterpret_cast<const b16x8*>(&sA1[(wr + i * 16 + lr) * 32 + ko]);
      }
#pragma unroll
      for (int j = 0; j < 2; ++j) {
        b0[j] = *reinterpret_cast<const b16x8*>(&sB0[(wc + j * 16 + lr) * 32 + ko]);
        b1[j] = *reinterpret_cast<const b16x8*>(&sB1[(wc + j * 16 + lr) * 32 + ko]);
      }
#pragma unroll
      for (int i = 0; i < 4; ++i)
#pragma unroll
        for (int j = 0; j < 2; ++j) {
          p0[i][j] = __builtin_amdgcn_mfma_f32_16x16x32_bf16(a0[i], b0[j], p0[i][j], 0, 0, 0);
          p1[i][j] = __builtin_amdgcn_mfma_f32_16x16x32_bf16(a1[i], b1[j], p1[i][j], 0, 0, 0);
        }
    }
#pragma unroll
    for (int j = 0; j < 2; ++j) {
      const int colg = bcol + wc + j * 16 + lr;
      const float c0 = bm0[(long long)r * 1600 + colg];
      const float c1 = bm1[(long long)r * 1600 + colg];
#pragma unroll
      for (int i = 0; i < 4; ++i)
#pragma unroll
        for (int q = 0; q < 4; ++q)
          zac[i][j][q] += (p0[i][j][q] + c0) * (p1[i][j][q] + c1);
    }
  }

  const int rbase = wr + (lane >> 4) * 4;
#pragma unroll
  for (int i = 0; i < 4; ++i)
#pragma unroll
    for (int j = 0; j < 2; ++j) {
      const int col = bcol + wc + j * 16 + lr;
#pragma unroll
      for (int q = 0; q < 4; ++q) {
        const long long row = brow + rbase + i * 16 + q;
        Z[row * 1600 + col] = f2bf(zac[i][j][q]);
      }
    }
}

// ---------------- per-row head: layer2 + slice/mask assembly ----------------
__global__ __launch_bounds__(256) void head_kernel(
    const float* __restrict__ T, const int* __restrict__ qtype,
    const float* __restrict__ W20, const float* __restrict__ b20,
    const float* __restrict__ W21, const float* __restrict__ b21,
    const float* __restrict__ W22, const float* __restrict__ b22,
    const float* __restrict__ W23, const float* __restrict__ b23,
    float* __restrict__ out) {
  const int b = blockIdx.x * 4 + (threadIdx.x >> 6);
  const int lane = threadIdx.x & 63;
  const int qt = qtype[b];
  const float* W2 = (qt == 0) ? W20 : (qt == 1) ? W21 : (qt == 2) ? W22 : W23;
  const float* b2 = (qt == 0) ? b20 : (qt == 1) ? b21 : (qt == 2) ? b22 : b23;
  const int lo = (qt == 2) ? 2 : (qt == 3) ? 7 : 0;
  const int hi = (qt == 3) ? 95 : (qt == 2) ? 7 : 2;
  const float* trow = T + (long long)b * 1024 + qt * 256;
  for (int c = lane; c < 95; c += 64) {
    float v = 0.f;
    if (c >= lo && c < hi) {
      const int jj = c - lo;
      const float* w = W2 + jj * 256;
      float acc = b2[jj];
      for (int k = 0; k < 256; k += 4) {
        const float4 tv = *reinterpret_cast<const float4*>(trow + k);
        const float4 wv = *reinterpret_cast<const float4*>(w + k);
        acc += tv.x * wv.x + tv.y * wv.y + tv.z * wv.z + tv.w * wv.w;
      }
      v = acc;
    }
    out[(long long)b * 95 + c] = v;
  }
}

// ---------------- launch ----------------

extern "C" void kernel_launch(void* const* d_in, const int* in_sizes, int n_in,
                              void* d_out, int out_size, void* d_ws, size_t ws_size,
                              hipStream_t stream) {
  (void)in_sizes; (void)n_in; (void)out_size; (void)ws_size;
  const float* input_v = (const float*)d_in[0];
  const float* input_q = (const float*)d_in[1];
  const int*   qtype   = (const int*)d_in[2];
  const float* Wv  = (const float*)d_in[3];  const float* bv  = (const float*)d_in[4];
  const float* Wq  = (const float*)d_in[5];  const float* bq  = (const float*)d_in[6];
  const float* W0  = (const float*)d_in[7];  const float* b0  = (const float*)d_in[8];
  const float* W1  = (const float*)d_in[9];  const float* b1  = (const float*)d_in[10];
  const float* Wm0 = (const float*)d_in[11]; const float* bm0 = (const float*)d_in[12];
  const float* Wm1 = (const float*)d_in[13]; const float* bm1 = (const float*)d_in[14];
  const float* Wo  = (const float*)d_in[15]; const float* bo  = (const float*)d_in[16];
  const float* cW1[4] = {(const float*)d_in[17], (const float*)d_in[21],
                         (const float*)d_in[25], (const float*)d_in[29]};
  const float* cb1[4] = {(const float*)d_in[18], (const float*)d_in[22],
                         (const float*)d_in[26], (const float*)d_in[30]};
  const float* cW2[4] = {(const float*)d_in[19], (const float*)d_in[23],
                         (const float*)d_in[27], (const float*)d_in[31]};
  const float* cb2[4] = {(const float*)d_in[20], (const float*)d_in[24],
                         (const float*)d_in[28], (const float*)d_in[32]};

  char* ws = (char*)d_ws;
  // persistent buffers
  u16*   XV  = (u16*)(ws + 0);          // [4096,1216] bf16
  u16*   XQ  = (u16*)(ws + 9961472);    // [4096,1216]
  u16*   H0  = (u16*)(ws + 19922944);   // [4096,1600]
  u16*   H1  = (u16*)(ws + 33030144);   // [4096,1600]
  u16*   ZB  = (u16*)(ws + 46137344);   // [4096,1600]
  u16*   XB  = (u16*)(ws + 59244544);   // [4096,1216]
  float* TB  = (float*)(ws + 69206016); // [4096,1024] f32
  float* BVP = (float*)(ws + 85983232); // [1280]
  float* BQP = (float*)(ws + 85988352); // [1280]
  float* B0P = (float*)(ws + 85993472); // [1664]
  float* B1P = (float*)(ws + 86000128); // [1664]
  float* BOP = (float*)(ws + 86006784); // [1280]
  float* B1C = (float*)(ws + 86011904); // [1024]
  char*  SCR = ws + 86016000;           // 153.6 MB reusable scratch

  const dim3 blk(256);
  auto cvt = [&](const float* s, u16* d, int Ns, int Ks, int Nd, int Kd) {
    long long total = ((long long)Nd * Kd) >> 3;
    cvt_pad_kernel<<<dim3((unsigned)((total + 255) / 256)), blk, 0, stream>>>(s, d, Ns, Ks, Nd, Kd);
  };
  auto padb = [&](const float* s, float* d, int Ns, int Nd) {
    pad_f32_kernel<<<dim3((unsigned)((Nd + 255) / 256)), blk, 0, stream>>>(s, d, Ns, Nd);
  };

  // biases
  padb(bv, BVP, 1200, 1280);
  padb(bq, BQP, 1200, 1280);
  padb(b0, B0P, 1600, 1664);
  padb(b1, B1P, 1600, 1664);
  padb(bo, BOP, 1200, 1280);
  for (int qt = 0; qt < 4; ++qt) padb(cb1[qt], B1C + qt * 256, 256, 256);

  // stage 1: x_v = tanh(input_v @ Wv^T + bv)
  {
    u16* INV = (u16*)SCR;                    // [4096,768]
    u16* WVB = (u16*)(SCR + 6291456);        // [1280,768]
    cvt(input_v, INV, 4096, 768, 4096, 768);
    cvt(Wv, WVB, 1200, 768, 1280, 768);
    gemm_bt_kernel<1, 1><<<dim3(10, 32), blk, 0, stream>>>(INV, WVB, BVP, XV, 768, 1200, 1216, 1216);
  }
  // stage 2: x_q = tanh(input_q @ Wq^T + bq)
  {
    u16* INQ = (u16*)SCR;                    // [4096,2400]
    u16* WQB = (u16*)(SCR + 19660800);       // [1280,2400]
    cvt(input_q, INQ, 4096, 2400, 4096, 2400);
    cvt(Wq, WQB, 1200, 2400, 1280, 2400);
    gemm_bt_kernel<1, 1><<<dim3(10, 32), blk, 0, stream>>>(INQ, WQB, BQP, XQ, 2400, 1200, 1216, 1216);
  }
  // stage 3: h0 = x_v @ W0^T + b0 ; h1 = x_q @ W1^T + b1
  {
    u16* W0B = (u16*)SCR;                    // [1664,1216]
    u16* W1B = (u16*)(SCR + 4046848);
    cvt(W0, W0B, 1600, 1200, 1664, 1216);
    cvt(W1, W1B, 1600, 1200, 1664, 1216);
    gemm_bt_kernel<0, 1><<<dim3(13, 32), blk, 0, stream>>>(XV, W0B, B0P, H0, 1216, 1600, 1600, 1600);
    gemm_bt_kernel<0, 1><<<dim3(13, 32), blk, 0, stream>>>(XQ, W1B, B1P, H1, 1216, 1600, 1600, 1600);
  }
  // stage 4: fused Mutan z
  {
    u16* WM0 = (u16*)SCR;                    // [24000,1600]
    u16* WM1 = (u16*)(SCR + 76800000);
    cvt(Wm0, WM0, 24000, 1600, 24000, 1600);
    cvt(Wm1, WM1, 24000, 1600, 24000, 1600);
    mutan_z_kernel<<<dim3(25, 32), blk, 0, stream>>>(H0, H1, WM0, WM1, bm0, bm1, ZB);
  }
  // stage 5: x = z @ Wo^T + bo
  {
    u16* WOB = (u16*)SCR;                    // [1280,1600]
    cvt(Wo, WOB, 1200, 1600, 1280, 1600);
    gemm_bt_kernel<0, 1><<<dim3(10, 32), blk, 0, stream>>>(ZB, WOB, BOP, XB, 1600, 1200, 1216, 1216);
  }
  // stage 6: t = tanh(x @ cW1cat^T + b1cat), all 4 heads batched (N=1024)
  {
    u16* CW1B = (u16*)SCR;                   // [1024,1216]
    for (int qt = 0; qt < 4; ++qt)
      cvt(cW1[qt], CW1B + (long long)qt * 256 * 1216, 256, 1200, 256, 1216);
    gemm_bt_kernel<1, 0><<<dim3(8, 32), blk, 0, stream>>>(XB, CW1B, B1C, TB, 1216, 1024, 1024, 1024);
  }
  // stage 7: layer2 + assemble final [4096,95]
  head_kernel<<<dim3(1024), blk, 0, stream>>>(TB, qtype,
      cW2[0], cb2[0], cW2[1], cb2[1], cW2[2], cb2[2], cW2[3], cb2[3],
      (float*)d_out);
}

// Round 2
// 1752.799 us; speedup vs baseline: 1.0773x; 1.0773x over previous
//
#include <hip/hip_runtime.h>

// MultiTaskVQAModel: v/q projections -> Mutan fusion (rank 15) -> per-question-type heads.
// bf16 MFMA pipeline, fp32 accumulate. B=4096.

using u16 = unsigned short;
typedef __bf16 b16x8 __attribute__((ext_vector_type(8)));
typedef float f32x4 __attribute__((ext_vector_type(4)));

static __device__ __forceinline__ u16 f2bf(float f) {
  unsigned int u = __builtin_bit_cast(unsigned int, f);
  u = (u + 0x7fffu + ((u >> 16) & 1u)) >> 16;   // round-to-nearest-even
  return (u16)u;
}

static __device__ __forceinline__ void gload_lds16(const u16* g, u16* l) {
  __builtin_amdgcn_global_load_lds((__attribute__((address_space(1))) void*)(g),
                                   (__attribute__((address_space(3))) void*)(l), 16, 0, 0);
}

// LDS tiles are [rows][4 slots of 8 bf16]. Slot swizzle: lin_slot holds global
// slot (lin ^ ((row>>1)&3)). Staging keeps LDS dest LINEAR (global_load_lds
// requirement) and pre-swizzles the global source; reads XOR the slot.
static __device__ __forceinline__ int lds_off(int row, int slot) {
  return row * 32 + ((slot ^ ((row >> 1) & 3)) << 3);
}

// ---------------- conversion / padding kernels ----------------

__global__ void cvt_pad_kernel(const float* __restrict__ src, u16* __restrict__ dst,
                               int Ns, int Ks, int Nd, int Kd) {
  long long idx = (long long)blockIdx.x * blockDim.x + threadIdx.x;
  long long total = ((long long)Nd * Kd) >> 3;
  if (idx >= total) return;
  long long e = idx << 3;
  int r = (int)(e / Kd);
  int c = (int)(e - (long long)r * Kd);
  u16 v[8];
  if (r < Ns && c + 8 <= Ks) {
    const float* s = src + (long long)r * Ks + c;
#pragma unroll
    for (int i = 0; i < 8; ++i) v[i] = f2bf(s[i]);
  } else {
#pragma unroll
    for (int i = 0; i < 8; ++i) {
      int cc = c + i;
      float f = (r < Ns && cc < Ks) ? src[(long long)r * Ks + cc] : 0.f;
      v[i] = f2bf(f);
    }
  }
  uint4 o;
  o.x = (unsigned)v[0] | ((unsigned)v[1] << 16);
  o.y = (unsigned)v[2] | ((unsigned)v[3] << 16);
  o.z = (unsigned)v[4] | ((unsigned)v[5] << 16);
  o.w = (unsigned)v[6] | ((unsigned)v[7] << 16);
  *reinterpret_cast<uint4*>(dst + e) = o;
}

__global__ void pad_f32_kernel(const float* __restrict__ src, float* __restrict__ dst,
                               int Ns, int Nd) {
  int i = blockIdx.x * blockDim.x + threadIdx.x;
  if (i < Nd) dst[i] = (i < Ns) ? src[i] : 0.f;
}

// ---------------- generic bf16 GEMM: C = act(A @ B^T + bias) ----------------
// A [M,K] bf16 (K%32==0), B [Npad,K] bf16 (Npad%128==0, zero-padded), bias f32
// 128x128 tile, 4 waves of 64x64, mfma 16x16x32.
template <int TANH, int OUT_BF16>
__global__ __launch_bounds__(256) void gemm_bt_kernel(
    const u16* __restrict__ A, const u16* __restrict__ B,
    const float* __restrict__ bias, void* __restrict__ Cv,
    int K, int Nout, int Nfill, int ldc) {
  __shared__ u16 sA[128 * 32];
  __shared__ u16 sB[128 * 32];
  const int tid = threadIdx.x;
  const int wid = tid >> 6;
  const int lane = tid & 63;
  const long long brow = (long long)blockIdx.y * 128;
  const long long bcol = (long long)blockIdx.x * 128;
  const int wr = (wid >> 1) * 64;
  const int wc = (wid & 1) * 64;
  const int lr = lane & 15;
  const int slot = lane >> 4;

  f32x4 acc[4][4];
#pragma unroll
  for (int i = 0; i < 4; ++i)
#pragma unroll
    for (int j = 0; j < 4; ++j)
#pragma unroll
      for (int q = 0; q < 4; ++q) acc[i][j][q] = 0.f;

  for (int k0 = 0; k0 < K; k0 += 32) {
    __syncthreads();
#pragma unroll
    for (int j = 0; j < 2; ++j) {
      const int c = j * 256 + tid;
      const int r = c >> 2;
      const int kc = ((c & 3) ^ ((r >> 1) & 3)) * 8;   // pre-swizzled source
      gload_lds16(A + (brow + r) * K + k0 + kc, sA + c * 8);
      gload_lds16(B + (bcol + r) * K + k0 + kc, sB + c * 8);
    }
    __syncthreads();
    b16x8 af[4], bfr[4];
#pragma unroll
    for (int i = 0; i < 4; ++i) {
      af[i]  = *reinterpret_cast<const b16x8*>(&sA[lds_off(wr + i * 16 + lr, slot)]);
      bfr[i] = *reinterpret_cast<const b16x8*>(&sB[lds_off(wc + i * 16 + lr, slot)]);
    }
#pragma unroll
    for (int i = 0; i < 4; ++i)
#pragma unroll
      for (int j = 0; j < 4; ++j)
        acc[i][j] = __builtin_amdgcn_mfma_f32_16x16x32_bf16(af[i], bfr[j], acc[i][j], 0, 0, 0);
  }

  const int rbase = wr + (lane >> 4) * 4;
#pragma unroll
  for (int i = 0; i < 4; ++i) {
#pragma unroll
    for (int j = 0; j < 4; ++j) {
      const long long col = bcol + wc + j * 16 + lr;
      if (col < Nfill) {
        const float bb = (col < Nout) ? bias[col] : 0.f;
#pragma unroll
        for (int q = 0; q < 4; ++q) {
          float v = acc[i][j][q] + bb;
          if (TANH) v = tanhf(v);
          if (col >= Nout) v = 0.f;
          const long long row = brow + rbase + i * 16 + q;
          if (OUT_BF16)
            reinterpret_cast<u16*>(Cv)[row * ldc + col] = f2bf(v);
          else
            reinterpret_cast<float*>(Cv)[row * ldc + col] = v;
        }
      }
    }
  }
}

// ---------------- fused Mutan z kernel ----------------
// z[b,d] = sum_r (h0@Wm0^T + bm0)[b, r*1600+d] * (h1@Wm1^T + bm1)[b, r*1600+d]
// tile: 128 (b) x 64 (d); 4 waves of 64x32; K = 1600.
// grid: x = row-tiles (32), y = col-tiles (25) so consecutive blocks share the
// same Wm column-slice (L2/L3 reuse of the 12.3 MB/col-tile weight panel).
__global__ __launch_bounds__(256) void mutan_z_kernel(
    const u16* __restrict__ H0, const u16* __restrict__ H1,
    const u16* __restrict__ Wm0, const u16* __restrict__ Wm1,
    const float* __restrict__ bm0, const float* __restrict__ bm1,
    u16* __restrict__ Z) {
  __shared__ u16 sA0[128 * 32], sA1[128 * 32], sB0[64 * 32], sB1[64 * 32];
  const int tid = threadIdx.x;
  const int wid = tid >> 6;
  const int lane = tid & 63;
  const long long brow = (long long)blockIdx.x * 128;
  const int bcol = blockIdx.y * 64;
  const int wr = (wid >> 1) * 64;
  const int wc = (wid & 1) * 32;
  const int lr = lane & 15;
  const int slot = lane >> 4;
  const int K = 1600;

  f32x4 zac[4][2];
#pragma unroll
  for (int i = 0; i < 4; ++i)
#pragma unroll
    for (int j = 0; j < 2; ++j)
#pragma unroll
      for (int q = 0; q < 4; ++q) zac[i][j][q] = 0.f;

  for (int r = 0; r < 15; ++r) {
    f32x4 p0[4][2], p1[4][2];
#pragma unroll
    for (int i = 0; i < 4; ++i)
#pragma unroll
      for (int j = 0; j < 2; ++j)
#pragma unroll
        for (int q = 0; q < 4; ++q) { p0[i][j][q] = 0.f; p1[i][j][q] = 0.f; }

    const long long wrow = (long long)r * 1600 + bcol;
    for (int k0 = 0; k0 < K; k0 += 32) {
      __syncthreads();
#pragma unroll
      for (int j = 0; j < 2; ++j) {
        const int c = j * 256 + tid;
        const int rr = c >> 2;
        const int kc = ((c & 3) ^ ((rr >> 1) & 3)) * 8;
        gload_lds16(H0 + (brow + rr) * K + k0 + kc, sA0 + c * 8);
        gload_lds16(H1 + (brow + rr) * K + k0 + kc, sA1 + c * 8);
      }
      {
        const int c = tid;
        const int rr = c >> 2;
        const int kc = ((c & 3) ^ ((rr >> 1) & 3)) * 8;
        gload_lds16(Wm0 + (wrow + rr) * K + k0 + kc, sB0 + c * 8);
        gload_lds16(Wm1 + (wrow + rr) * K + k0 + kc, sB1 + c * 8);
      }
      __syncthreads();
      b16x8 a0[4], a1[4], b0[2], b1[2];
#pragma unroll
      for (int i = 0; i < 4; ++i) {
        a0[i] = *reinterpret_cast<const b16x8*>(&sA0[lds_off(wr + i * 16 + lr, slot)]);
        a1[i] = *reinterpret_cast<const b16x8*>(&sA1[lds_off(wr + i * 16 + lr, slot)]);
      }
#pragma unroll
      for (int j = 0; j < 2; ++j) {
        b0[j] = *reinterpret_cast<const b16x8*>(&sB0[lds_off(wc + j * 16 + lr, slot)]);
        b1[j] = *reinterpret_cast<const b16x8*>(&sB1[lds_off(wc + j * 16 + lr, slot)]);
      }
#pragma unroll
      for (int i = 0; i < 4; ++i)
#pragma unroll
        for (int j = 0; j < 2; ++j) {
          p0[i][j] = __builtin_amdgcn_mfma_f32_16x16x32_bf16(a0[i], b0[j], p0[i][j], 0, 0, 0);
          p1[i][j] = __builtin_amdgcn_mfma_f32_16x16x32_bf16(a1[i], b1[j], p1[i][j], 0, 0, 0);
        }
    }
#pragma unroll
    for (int j = 0; j < 2; ++j) {
      const int colg = bcol + wc + j * 16 + lr;
      const float c0 = bm0[(long long)r * 1600 + colg];
      const float c1 = bm1[(long long)r * 1600 + colg];
#pragma unroll
      for (int i = 0; i < 4; ++i)
#pragma unroll
        for (int q = 0; q < 4; ++q)
          zac[i][j][q] += (p0[i][j][q] + c0) * (p1[i][j][q] + c1);
    }
  }

  const int rbase = wr + (lane >> 4) * 4;
#pragma unroll
  for (int i = 0; i < 4; ++i)
#pragma unroll
    for (int j = 0; j < 2; ++j) {
      const int col = bcol + wc + j * 16 + lr;
#pragma unroll
      for (int q = 0; q < 4; ++q) {
        const long long row = brow + rbase + i * 16 + q;
        Z[row * 1600 + col] = f2bf(zac[i][j][q]);
      }
    }
}

// ---------------- per-row head: layer2 + slice/mask assembly ----------------
__global__ __launch_bounds__(256) void head_kernel(
    const float* __restrict__ T, const int* __restrict__ qtype,
    const float* __restrict__ W20, const float* __restrict__ b20,
    const float* __restrict__ W21, const float* __restrict__ b21,
    const float* __restrict__ W22, const float* __restrict__ b22,
    const float* __restrict__ W23, const float* __restrict__ b23,
    float* __restrict__ out) {
  const int b = blockIdx.x * 4 + (threadIdx.x >> 6);
  const int lane = threadIdx.x & 63;
  const int qt = qtype[b];
  const float* W2 = (qt == 0) ? W20 : (qt == 1) ? W21 : (qt == 2) ? W22 : W23;
  const float* b2 = (qt == 0) ? b20 : (qt == 1) ? b21 : (qt == 2) ? b22 : b23;
  const int lo = (qt == 2) ? 2 : (qt == 3) ? 7 : 0;
  const int hi = (qt == 3) ? 95 : (qt == 2) ? 7 : 2;
  const float* trow = T + (long long)b * 1024 + qt * 256;
  for (int c = lane; c < 95; c += 64) {
    float v = 0.f;
    if (c >= lo && c < hi) {
      const int jj = c - lo;
      const float* w = W2 + jj * 256;
      float acc = b2[jj];
      for (int k = 0; k < 256; k += 4) {
        const float4 tv = *reinterpret_cast<const float4*>(trow + k);
        const float4 wv = *reinterpret_cast<const float4*>(w + k);
        acc += tv.x * wv.x + tv.y * wv.y + tv.z * wv.z + tv.w * wv.w;
      }
      v = acc;
    }
    out[(long long)b * 95 + c] = v;
  }
}

// ---------------- launch ----------------

extern "C" void kernel_launch(void* const* d_in, const int* in_sizes, int n_in,
                              void* d_out, int out_size, void* d_ws, size_t ws_size,
                              hipStream_t stream) {
  (void)in_sizes; (void)n_in; (void)out_size; (void)ws_size;
  const float* input_v = (const float*)d_in[0];
  const float* input_q = (const float*)d_in[1];
  const int*   qtype   = (const int*)d_in[2];
  const float* Wv  = (const float*)d_in[3];  const float* bv  = (const float*)d_in[4];
  const float* Wq  = (const float*)d_in[5];  const float* bq  = (const float*)d_in[6];
  const float* W0  = (const float*)d_in[7];  const float* b0  = (const float*)d_in[8];
  const float* W1  = (const float*)d_in[9];  const float* b1  = (const float*)d_in[10];
  const float* Wm0 = (const float*)d_in[11]; const float* bm0 = (const float*)d_in[12];
  const float* Wm1 = (const float*)d_in[13]; const float* bm1 = (const float*)d_in[14];
  const float* Wo  = (const float*)d_in[15]; const float* bo  = (const float*)d_in[16];
  const float* cW1[4] = {(const float*)d_in[17], (const float*)d_in[21],
                         (const float*)d_in[25], (const float*)d_in[29]};
  const float* cb1[4] = {(const float*)d_in[18], (const float*)d_in[22],
                         (const float*)d_in[26], (const float*)d_in[30]};
  const float* cW2[4] = {(const float*)d_in[19], (const float*)d_in[23],
                         (const float*)d_in[27], (const float*)d_in[31]};
  const float* cb2[4] = {(const float*)d_in[20], (const float*)d_in[24],
                         (const float*)d_in[28], (const float*)d_in[32]};

  char* ws = (char*)d_ws;
  // persistent buffers
  u16*   XV  = (u16*)(ws + 0);          // [4096,1216] bf16
  u16*   XQ  = (u16*)(ws + 9961472);    // [4096,1216]
  u16*   H0  = (u16*)(ws + 19922944);   // [4096,1600]
  u16*   H1  = (u16*)(ws + 33030144);   // [4096,1600]
  u16*   ZB  = (u16*)(ws + 46137344);   // [4096,1600]
  u16*   XB  = (u16*)(ws + 59244544);   // [4096,1216]
  float* TB  = (float*)(ws + 69206016); // [4096,1024] f32
  float* BVP = (float*)(ws + 85983232); // [1280]
  float* BQP = (float*)(ws + 85988352); // [1280]
  float* B0P = (float*)(ws + 85993472); // [1664]
  float* B1P = (float*)(ws + 86000128); // [1664]
  float* BOP = (float*)(ws + 86006784); // [1280]
  float* B1C = (float*)(ws + 86011904); // [1024]
  char*  SCR = ws + 86016000;           // 153.6 MB reusable scratch

  const dim3 blk(256);
  auto cvt = [&](const float* s, u16* d, int Ns, int Ks, int Nd, int Kd) {
    long long total = ((long long)Nd * Kd) >> 3;
    cvt_pad_kernel<<<dim3((unsigned)((total + 255) / 256)), blk, 0, stream>>>(s, d, Ns, Ks, Nd, Kd);
  };
  auto padb = [&](const float* s, float* d, int Ns, int Nd) {
    pad_f32_kernel<<<dim3((unsigned)((Nd + 255) / 256)), blk, 0, stream>>>(s, d, Ns, Nd);
  };

  // biases
  padb(bv, BVP, 1200, 1280);
  padb(bq, BQP, 1200, 1280);
  padb(b0, B0P, 1600, 1664);
  padb(b1, B1P, 1600, 1664);
  padb(bo, BOP, 1200, 1280);
  for (int qt = 0; qt < 4; ++qt) padb(cb1[qt], B1C + qt * 256, 256, 256);

  // stage 1: x_v = tanh(input_v @ Wv^T + bv)
  {
    u16* INV = (u16*)SCR;                    // [4096,768]
    u16* WVB = (u16*)(SCR + 6291456);        // [1280,768]
    cvt(input_v, INV, 4096, 768, 4096, 768);
    cvt(Wv, WVB, 1200, 768, 1280, 768);
    gemm_bt_kernel<1, 1><<<dim3(10, 32), blk, 0, stream>>>(INV, WVB, BVP, XV, 768, 1200, 1216, 1216);
  }
  // stage 2: x_q = tanh(input_q @ Wq^T + bq)
  {
    u16* INQ = (u16*)SCR;                    // [4096,2400]
    u16* WQB = (u16*)(SCR + 19660800);       // [1280,2400]
    cvt(input_q, INQ, 4096, 2400, 4096, 2400);
    cvt(Wq, WQB, 1200, 2400, 1280, 2400);
    gemm_bt_kernel<1, 1><<<dim3(10, 32), blk, 0, stream>>>(INQ, WQB, BQP, XQ, 2400, 1200, 1216, 1216);
  }
  // stage 3: h0 = x_v @ W0^T + b0 ; h1 = x_q @ W1^T + b1
  {
    u16* W0B = (u16*)SCR;                    // [1664,1216]
    u16* W1B = (u16*)(SCR + 4046848);
    cvt(W0, W0B, 1600, 1200, 1664, 1216);
    cvt(W1, W1B, 1600, 1200, 1664, 1216);
    gemm_bt_kernel<0, 1><<<dim3(13, 32), blk, 0, stream>>>(XV, W0B, B0P, H0, 1216, 1600, 1600, 1600);
    gemm_bt_kernel<0, 1><<<dim3(13, 32), blk, 0, stream>>>(XQ, W1B, B1P, H1, 1216, 1600, 1600, 1600);
  }
  // stage 4: fused Mutan z (grid: x=row-tiles, y=col-tiles for Wm L2/L3 reuse)
  {
    u16* WM0 = (u16*)SCR;                    // [24000,1600]
    u16* WM1 = (u16*)(SCR + 76800000);
    cvt(Wm0, WM0, 24000, 1600, 24000, 1600);
    cvt(Wm1, WM1, 24000, 1600, 24000, 1600);
    mutan_z_kernel<<<dim3(32, 25), blk, 0, stream>>>(H0, H1, WM0, WM1, bm0, bm1, ZB);
  }
  // stage 5: x = z @ Wo^T + bo
  {
    u16* WOB = (u16*)SCR;                    // [1280,1600]
    cvt(Wo, WOB, 1200, 1600, 1280, 1600);
    gemm_bt_kernel<0, 1><<<dim3(10, 32), blk, 0, stream>>>(ZB, WOB, BOP, XB, 1600, 1200, 1216, 1216);
  }
  // stage 6: t = tanh(x @ cW1cat^T + b1cat), all 4 heads batched (N=1024)
  {
    u16* CW1B = (u16*)SCR;                   // [1024,1216]
    for (int qt = 0; qt < 4; ++qt)
      cvt(cW1[qt], CW1B + (long long)qt * 256 * 1216, 256, 1200, 256, 1216);
    gemm_bt_kernel<1, 0><<<dim3(8, 32), blk, 0, stream>>>(XB, CW1B, B1C, TB, 1216, 1024, 1024, 1024);
  }
  // stage 7: layer2 + assemble final [4096,95]
  head_kernel<<<dim3(1024), blk, 0, stream>>>(TB, qtype,
      cW2[0], cb2[0], cW2[1], cb2[1], cW2[2], cb2[2], cW2[3], cb2[3],
      (float*)d_out);
}